// Round 2
// baseline (166.087 us; speedup 1.0000x reference)
//
#include <hip/hip_runtime.h>
#include <math.h>

#define MM 64
#define NA 24
#define NP 276
#define NT 6000
#define NKPAD 288
#define QC 0.22360679774997896f
#define EXPC 0.01666666666666667f  // 5/(3*sig^2), sig=10

// ws layout (float offsets)
#define OFF_XS   0                 // 64*276
#define OFF_UU   17664             // 64
#define OFF_VV   17728             // 6000
#define OFF_C1   23728             // 6000
#define OFF_F1P  29728             // 64*276 (zeroed)
#define OFF_F2   47392             // 64*276 (zeroed)
#define OFF_ES   65056             // 64     (zeroed)
#define OFF_SW   65120             // 64     (zeroed)
#define OFF_W    65184             // 64*6000
#define OFF_E1   449184            // 64*6000
#define ZTOT     35456             // floats to zero starting at OFF_F1P

// ---------- kernel 1: prep (xs, uu) + stats (vv, c1) + zero accumulators ----------
__global__ __launch_bounds__(256) void k_pre(const float* __restrict__ Rs,
                                             const float* __restrict__ xt,
                                             const float* __restrict__ Ja,
                                             float* __restrict__ ws) {
  const int tid = threadIdx.x;
  // zero F1p/F2/es/sw (all blocks participate; single pass since grid*256 > ZTOT)
  for (int z = blockIdx.x * 256 + tid; z < ZTOT; z += gridDim.x * 256)
    ws[OFF_F1P + z] = 0.f;

  if (blockIdx.x < MM) {
    const int m = blockIdx.x;
    __shared__ float sR[NA * 3];
    __shared__ float sAcc[4];
    if (tid < NA * 3) sR[tid] = Rs[m * NA * 3 + tid];
    __syncthreads();
    float acc = 0.f;
    for (int p = tid; p < NP; p += 256) {
      int i = (int)((1.0f + sqrtf(1.0f + 8.0f * (float)p)) * 0.5f);
      while (i * (i - 1) / 2 > p) i--;
      while ((i + 1) * i / 2 <= p) i++;
      int j = p - i * (i - 1) / 2;
      float dx = sR[i * 3 + 0] - sR[j * 3 + 0];
      float dy = sR[i * 3 + 1] - sR[j * 3 + 1];
      float dz = sR[i * 3 + 2] - sR[j * 3 + 2];
      float u = 1.0f / sqrtf(dx * dx + dy * dy + dz * dz);
      ws[OFF_XS + m * NP + p] = u;
      acc += u * u;
    }
    for (int off = 32; off; off >>= 1) acc += __shfl_down(acc, off);
    if ((tid & 63) == 0) sAcc[tid >> 6] = acc;
    __syncthreads();
    if (tid == 0) ws[OFF_UU + m] = sAcc[0] + sAcc[1] + sAcc[2] + sAcc[3];
  } else {
    const int t = (blockIdx.x - MM) * 4 + (tid >> 6);
    const int lane = tid & 63;
    if (t < NT) {
      const float* vrow = xt + t * NP;
      const float* jrow = Ja + t * NP;
      float a = 0.f, b = 0.f;
      for (int p = lane; p < NP; p += 64) {
        float v = vrow[p], j = jrow[p];
        a += v * v;
        b += v * j;
      }
      for (int off = 32; off; off >>= 1) {
        a += __shfl_down(a, off);
        b += __shfl_down(b, off);
      }
      if (lane == 0) { ws[OFF_VV + t] = a; ws[OFF_C1 + t] = b; }
    }
  }
}

// ---------- kernel 2: fused GEMM1 + elementwise ----------
// tile 64m x 16t, K = 276 (padded 288), per-thread 4m x 2t x 2mat
// writes w[m][t], e1[m][t]; atomically accumulates es, sumw per m
__global__ __launch_bounds__(128) void k_g1(const float* __restrict__ xt,
                                            const float* __restrict__ Ja,
                                            float* __restrict__ ws) {
  __shared__ __align__(16) float As[16][68];    // [k][m], pad 68: writes 2-way, reads clean
  __shared__ __align__(16) float2 Bs[16][18];   // [k][t]=(v,j), pad 18: 144B rows, 16B-aligned
  const int tid = threadIdx.x;
  const int t0 = blockIdx.x * 16;
  const int c = tid & 7;        // t-pair
  const int r = tid >> 3;       // m-group (4m)
  const int am = tid >> 2;      // A staging row (and +32)
  const int akg = tid & 3;      // A k-group
  const int bmat = tid >> 6;    // 0: xt, 1: Ja
  const int bt = (tid & 63) >> 2;
  const int bkg = tid & 3;
  const float* xs = ws + OFF_XS;
  const float* bsrc = bmat ? Ja : xt;

  const float4 uu4 = *(const float4*)(ws + OFF_UU + r * 4);
  const float2 vv2 = *(const float2*)(ws + OFF_VV + t0 + c * 2);
  const float2 c12 = *(const float2*)(ws + OFF_C1 + t0 + c * 2);

  float accv[2][4] = {{0.f,0.f,0.f,0.f},{0.f,0.f,0.f,0.f}};
  float accj[2][4] = {{0.f,0.f,0.f,0.f},{0.f,0.f,0.f,0.f}};

  for (int p0 = 0; p0 < NKPAD; p0 += 16) {
    const int pa = p0 + akg * 4;
    float4 a0 = make_float4(0.f, 0.f, 0.f, 0.f), a1 = a0, bv = a0;
    if (pa < NP) {  // pa multiple of 4, NP%4==0 -> full float4 in-bounds
      a0 = *(const float4*)(xs + am * NP + pa);
      a1 = *(const float4*)(xs + (am + 32) * NP + pa);
    }
    const int pb = p0 + bkg * 4;
    if (pb < NP) bv = *(const float4*)(bsrc + (t0 + bt) * NP + pb);
    __syncthreads();
    As[akg * 4 + 0][am] = a0.x; As[akg * 4 + 1][am] = a0.y;
    As[akg * 4 + 2][am] = a0.z; As[akg * 4 + 3][am] = a0.w;
    As[akg * 4 + 0][am + 32] = a1.x; As[akg * 4 + 1][am + 32] = a1.y;
    As[akg * 4 + 2][am + 32] = a1.z; As[akg * 4 + 3][am + 32] = a1.w;
    if (bmat == 0) {
      Bs[bkg * 4 + 0][bt].x = bv.x; Bs[bkg * 4 + 1][bt].x = bv.y;
      Bs[bkg * 4 + 2][bt].x = bv.z; Bs[bkg * 4 + 3][bt].x = bv.w;
    } else {
      Bs[bkg * 4 + 0][bt].y = bv.x; Bs[bkg * 4 + 1][bt].y = bv.y;
      Bs[bkg * 4 + 2][bt].y = bv.z; Bs[bkg * 4 + 3][bt].y = bv.w;
    }
    __syncthreads();
#pragma unroll
    for (int k = 0; k < 16; k++) {
      const float4 a = *(const float4*)&As[k][r * 4];
      const float4 b = *(const float4*)&Bs[k][c * 2];  // (v0, j0, v1, j1)
      const float av[4] = {a.x, a.y, a.z, a.w};
#pragma unroll
      for (int i = 0; i < 4; i++) {
        accv[0][i] = fmaf(av[i], b.x, accv[0][i]);
        accj[0][i] = fmaf(av[i], b.y, accj[0][i]);
        accv[1][i] = fmaf(av[i], b.z, accv[1][i]);
        accj[1][i] = fmaf(av[i], b.w, accj[1][i]);
      }
    }
  }

  // fused elementwise epilogue
  float wv[2][4], ev[2][4];
  float es_m[4] = {0.f, 0.f, 0.f, 0.f}, sw_m[4] = {0.f, 0.f, 0.f, 0.f};
  const float uuv[4] = {uu4.x, uu4.y, uu4.z, uu4.w};
#pragma unroll
  for (int tt = 0; tt < 2; tt++) {
    const float vvt = tt ? vv2.y : vv2.x;
    const float c1t = tt ? c12.y : c12.x;
#pragma unroll
    for (int i = 0; i < 4; i++) {
      float g1 = accv[tt][i], g2 = accj[tt][i];
      float d2 = fmaxf(uuv[i] - 2.f * g1 + vvt, 0.f);
      float xd = QC * sqrtf(d2);
      float dv = QC * (g2 - c1t);
      float ex = EXPC * __expf(-xd);
      float e1v = ex * (1.f + xd);
      float w_ = ex * dv;
      wv[tt][i] = w_; ev[tt][i] = e1v;
      es_m[i] += e1v * dv;
      sw_m[i] += w_;
    }
  }
  float* wout = ws + OFF_W;
  float* eout = ws + OFF_E1;
#pragma unroll
  for (int i = 0; i < 4; i++) {
    const int m = r * 4 + i;
    *(float2*)(wout + m * NT + t0 + c * 2) = make_float2(wv[0][i], wv[1][i]);
    *(float2*)(eout + m * NT + t0 + c * 2) = make_float2(ev[0][i], ev[1][i]);
  }
  // reduce over the 8 t-lanes of each m-group, then atomics
#pragma unroll
  for (int off = 4; off; off >>= 1) {
#pragma unroll
    for (int i = 0; i < 4; i++) {
      es_m[i] += __shfl_down(es_m[i], off);
      sw_m[i] += __shfl_down(sw_m[i], off);
    }
  }
  if (c == 0) {
#pragma unroll
    for (int i = 0; i < 4; i++) {
      atomicAdd(ws + OFF_ES + r * 4 + i, es_m[i]);
      atomicAdd(ws + OFF_SW + r * 4 + i, sw_m[i]);
    }
  }
}

// ---------- kernel 3: GEMM2 F1p = w @ xt, F2 = e1 @ Ja ----------
// tile 64m x 32p, K-chunk 128 (47 chunks), per-thread 8m x 2p x 2mat, atomic K-reduce
__global__ __launch_bounds__(128) void k_g2(const float* __restrict__ xt,
                                            const float* __restrict__ Ja,
                                            float* __restrict__ ws) {
  __shared__ __align__(16) float2 As[16][66];  // [k][m]=(w,e1), pad 66: 528B rows
  __shared__ __align__(16) float2 Bs[16][34];  // [k][p]=(v,j),  pad 34: 272B rows
  const float* w  = ws + OFF_W;
  const float* e1 = ws + OFF_E1;
  const int tid = threadIdx.x;
  const int p0 = blockIdx.x * 32;
  const int k0 = blockIdx.y * 128;
  const int c = tid & 15;       // p-pair
  const int r = tid >> 4;       // m-group (8m)
  const int am = tid >> 2;      // A staging row (and +32)
  const int akg = tid & 3;
  const int bmat = tid >> 6;
  const int bk = (tid & 63) >> 3;  // and +8
  const int bpg = tid & 7;
  const float* bsrc = bmat ? Ja : xt;

  float acc1[2][8] = {{0.f,0.f,0.f,0.f,0.f,0.f,0.f,0.f},{0.f,0.f,0.f,0.f,0.f,0.f,0.f,0.f}};
  float acc2[2][8] = {{0.f,0.f,0.f,0.f,0.f,0.f,0.f,0.f},{0.f,0.f,0.f,0.f,0.f,0.f,0.f,0.f}};

  for (int kk = k0; kk < k0 + 128; kk += 16) {
    const int tg = kk + akg * 4;
    float4 w0 = make_float4(0.f, 0.f, 0.f, 0.f), w1 = w0, e0 = w0, ee = w0;
    if (tg < NT) {  // tg multiple of 4, NT%4==0
      w0 = *(const float4*)(w  + am * NT + tg);
      w1 = *(const float4*)(w  + (am + 32) * NT + tg);
      e0 = *(const float4*)(e1 + am * NT + tg);
      ee = *(const float4*)(e1 + (am + 32) * NT + tg);
    }
    const int pg = p0 + bpg * 4;
    float4 b0 = make_float4(0.f, 0.f, 0.f, 0.f), b1 = b0;
    const int kg0 = kk + bk, kg1 = kk + bk + 8;
    if (pg < NP) {
      if (kg0 < NT) b0 = *(const float4*)(bsrc + kg0 * NP + pg);
      if (kg1 < NT) b1 = *(const float4*)(bsrc + kg1 * NP + pg);
    }
    __syncthreads();
    As[akg * 4 + 0][am].x = w0.x; As[akg * 4 + 1][am].x = w0.y;
    As[akg * 4 + 2][am].x = w0.z; As[akg * 4 + 3][am].x = w0.w;
    As[akg * 4 + 0][am].y = e0.x; As[akg * 4 + 1][am].y = e0.y;
    As[akg * 4 + 2][am].y = e0.z; As[akg * 4 + 3][am].y = e0.w;
    As[akg * 4 + 0][am + 32].x = w1.x; As[akg * 4 + 1][am + 32].x = w1.y;
    As[akg * 4 + 2][am + 32].x = w1.z; As[akg * 4 + 3][am + 32].x = w1.w;
    As[akg * 4 + 0][am + 32].y = ee.x; As[akg * 4 + 1][am + 32].y = ee.y;
    As[akg * 4 + 2][am + 32].y = ee.z; As[akg * 4 + 3][am + 32].y = ee.w;
    if (bmat == 0) {
      Bs[bk][bpg * 4 + 0].x = b0.x; Bs[bk][bpg * 4 + 1].x = b0.y;
      Bs[bk][bpg * 4 + 2].x = b0.z; Bs[bk][bpg * 4 + 3].x = b0.w;
      Bs[bk + 8][bpg * 4 + 0].x = b1.x; Bs[bk + 8][bpg * 4 + 1].x = b1.y;
      Bs[bk + 8][bpg * 4 + 2].x = b1.z; Bs[bk + 8][bpg * 4 + 3].x = b1.w;
    } else {
      Bs[bk][bpg * 4 + 0].y = b0.x; Bs[bk][bpg * 4 + 1].y = b0.y;
      Bs[bk][bpg * 4 + 2].y = b0.z; Bs[bk][bpg * 4 + 3].y = b0.w;
      Bs[bk + 8][bpg * 4 + 0].y = b1.x; Bs[bk + 8][bpg * 4 + 1].y = b1.y;
      Bs[bk + 8][bpg * 4 + 2].y = b1.z; Bs[bk + 8][bpg * 4 + 3].y = b1.w;
    }
    __syncthreads();
#pragma unroll
    for (int k = 0; k < 16; k++) {
      const float4 b = *(const float4*)&Bs[k][c * 2];  // (v0, j0, v1, j1)
#pragma unroll
      for (int j = 0; j < 4; j++) {
        const float4 A = *(const float4*)&As[k][r * 8 + 2 * j];  // (w0,e0,w1,e1) for m=2j,2j+1
        acc1[0][2 * j]     = fmaf(A.x, b.x, acc1[0][2 * j]);
        acc2[0][2 * j]     = fmaf(A.y, b.y, acc2[0][2 * j]);
        acc1[1][2 * j]     = fmaf(A.x, b.z, acc1[1][2 * j]);
        acc2[1][2 * j]     = fmaf(A.y, b.w, acc2[1][2 * j]);
        acc1[0][2 * j + 1] = fmaf(A.z, b.x, acc1[0][2 * j + 1]);
        acc2[0][2 * j + 1] = fmaf(A.w, b.y, acc2[0][2 * j + 1]);
        acc1[1][2 * j + 1] = fmaf(A.z, b.z, acc1[1][2 * j + 1]);
        acc2[1][2 * j + 1] = fmaf(A.w, b.w, acc2[1][2 * j + 1]);
      }
    }
  }
  float* F1p = ws + OFF_F1P;
  float* F2  = ws + OFF_F2;
#pragma unroll
  for (int pp = 0; pp < 2; pp++) {
    const int p = p0 + c * 2 + pp;
    if (p < NP) {
#pragma unroll
      for (int i = 0; i < 8; i++) {
        atomicAdd(&F1p[(r * 8 + i) * NP + p], acc1[pp][i]);
        atomicAdd(&F2[(r * 8 + i) * NP + p],  acc2[pp][i]);
      }
    }
  }
}

// ---------- kernel 4: finalize ----------
__global__ __launch_bounds__(320) void k_final(const float* __restrict__ Rs,
                                               const float* __restrict__ ws,
                                               float* __restrict__ out) {
  const int m = blockIdx.x;
  const int tid = threadIdx.x;
  __shared__ float fx[NP];
  __shared__ float sR[NA * 3];
  if (tid < NA * 3) sR[tid] = Rs[m * NA * 3 + tid];
  const float sw = ws[OFF_SW + m];
  for (int p = tid; p < NP; p += 320) {
    float u = ws[OFF_XS + m * NP + p];
    float F1 = QC * (u * sw - ws[OFF_F1P + m * NP + p]);
    fx[p] = (F1 - ws[OFF_F2 + m * NP + p]) * u * u * u;
  }
  __syncthreads();
  if (tid == 0) out[m] = ws[OFF_ES + m] / QC;  // *STD + C, STD=1, C=0
  if (tid < NA * 3) {
    const int a = tid / 3, cc = tid % 3;
    const float ra = sR[a * 3 + cc];
    float acc = 0.f;
    for (int b = 0; b < NA; b++) {
      if (b == a) continue;
      const int i = a > b ? a : b, j = a > b ? b : a;
      const int p = i * (i - 1) / 2 + j;
      acc += (sR[b * 3 + cc] - ra) * fx[p];
    }
    out[MM + m * NA * 3 + tid] = acc;
  }
}

extern "C" void kernel_launch(void* const* d_in, const int* in_sizes, int n_in,
                              void* d_out, int out_size, void* d_ws, size_t ws_size,
                              hipStream_t stream) {
  const float* Rs = (const float*)d_in[0];
  const float* xt = (const float*)d_in[1];
  const float* Ja = (const float*)d_in[2];
  float* out = (float*)d_out;
  float* ws = (float*)d_ws;

  k_pre<<<MM + NT / 4, 256, 0, stream>>>(Rs, xt, Ja, ws);
  k_g1<<<NT / 16, 128, 0, stream>>>(xt, Ja, ws);
  k_g2<<<dim3(9, 47), 128, 0, stream>>>(xt, Ja, ws);
  k_final<<<MM, 320, 0, stream>>>(Rs, ws, out);
}

// Round 3
// 163.043 us; speedup vs baseline: 1.0187x; 1.0187x over previous
//
#include <hip/hip_runtime.h>
#include <math.h>

#define MM 64
#define NA 24
#define NP 276
#define NT 6000
#define QC 0.22360679774997896f
#define EXPC 0.01666666666666667f  // 5/(3*sig^2), sig=10

// ws layout (float offsets)
#define OFF_XS   0                 // 64*276
#define OFF_UU   17664             // 64
#define OFF_VV   17728             // 6000
#define OFF_C1   23728             // 6000
#define OFF_F1P  29728             // 64*276 (zeroed)
#define OFF_F2   47392             // 64*276 (zeroed)
#define OFF_ES   65056             // 64     (zeroed)
#define OFF_SW   65120             // 64     (zeroed)
#define OFF_W    65184             // 64*6000
#define OFF_E1   449184            // 64*6000
#define ZTOT     35456             // floats to zero at OFF_F1P

__device__ __forceinline__ float f4c(const float4& v, int i) {
  return i == 0 ? v.x : i == 1 ? v.y : i == 2 ? v.z : v.w;
}

// ---------- kernel 1: prep (xs, uu) + stats (vv, c1) + zero accumulators ----------
__global__ __launch_bounds__(256) void k_pre(const float* __restrict__ Rs,
                                             const float* __restrict__ xt,
                                             const float* __restrict__ Ja,
                                             float* __restrict__ ws) {
  const int tid = threadIdx.x;
  for (int z = blockIdx.x * 256 + tid; z < ZTOT; z += gridDim.x * 256)
    ws[OFF_F1P + z] = 0.f;

  if (blockIdx.x < MM) {
    const int m = blockIdx.x;
    __shared__ float sR[NA * 3];
    __shared__ float sAcc[4];
    if (tid < NA * 3) sR[tid] = Rs[m * NA * 3 + tid];
    __syncthreads();
    float acc = 0.f;
    for (int p = tid; p < NP; p += 256) {
      int i = (int)((1.0f + sqrtf(1.0f + 8.0f * (float)p)) * 0.5f);
      while (i * (i - 1) / 2 > p) i--;
      while ((i + 1) * i / 2 <= p) i++;
      int j = p - i * (i - 1) / 2;
      float dx = sR[i * 3 + 0] - sR[j * 3 + 0];
      float dy = sR[i * 3 + 1] - sR[j * 3 + 1];
      float dz = sR[i * 3 + 2] - sR[j * 3 + 2];
      float u = 1.0f / sqrtf(dx * dx + dy * dy + dz * dz);
      ws[OFF_XS + m * NP + p] = u;
      acc += u * u;
    }
    for (int off = 32; off; off >>= 1) acc += __shfl_down(acc, off);
    if ((tid & 63) == 0) sAcc[tid >> 6] = acc;
    __syncthreads();
    if (tid == 0) ws[OFF_UU + m] = sAcc[0] + sAcc[1] + sAcc[2] + sAcc[3];
  } else {
    const int t = (blockIdx.x - MM) * 4 + (tid >> 6);
    const int lane = tid & 63;
    if (t < NT) {
      const float* vrow = xt + (size_t)t * NP;
      const float* jrow = Ja + (size_t)t * NP;
      float a = 0.f, b = 0.f;
      for (int p = lane; p < NP; p += 64) {
        float v = vrow[p], j = jrow[p];
        a += v * v;
        b += v * j;
      }
      for (int off = 32; off; off >>= 1) {
        a += __shfl_down(a, off);
        b += __shfl_down(b, off);
      }
      if (lane == 0) { ws[OFF_VV + t] = a; ws[OFF_C1 + t] = b; }
    }
  }
}

// ---------- kernel 2: fused GEMM1 + elementwise ----------
// out tile 64m x 16t; FULL K=276 staged in LDS once (B = xt,Ja interleaved);
// A (xs) streamed from L2 with register double-buffer; NO barriers in K-loop.
#define G1_TD 16
#define G1_STR 278  // float2 per t-row (276 + 2 pad); 556 floats, 556%32=12
__global__ __launch_bounds__(256) void k_g1(const float* __restrict__ xt,
                                            const float* __restrict__ Ja,
                                            float* __restrict__ ws) {
  __shared__ __align__(16) float2 Bs[G1_TD][G1_STR];
  const int tid = threadIdx.x;
  const int t0 = blockIdx.x * G1_TD;
  const int c = tid & 15;   // t-column
  const int r = tid >> 4;   // m-group: m = 4r..4r+3

  // stage B: thread (row = tid>>4, kg = tid&15) loads float2 of xt and Ja
  {
    const int row = tid >> 4;
    const int kg = tid & 15;
    const float* xrow = xt + (size_t)(t0 + row) * NP;
    const float* jrow = Ja + (size_t)(t0 + row) * NP;
#pragma unroll
    for (int it = 0; it < 9; it++) {
      const int k = kg * 2 + it * 32;
      if (k < NP) {
        float2 v = *(const float2*)(xrow + k);
        float2 j = *(const float2*)(jrow + k);
        *(float4*)(&Bs[row][k]) = make_float4(v.x, j.x, v.y, j.y);
      }
    }
  }
  const float* xs = ws + OFF_XS;
  const float4 uu4 = *(const float4*)(ws + OFF_UU + r * 4);
  const float vvt = ws[OFF_VV + t0 + c];
  const float c1t = ws[OFF_C1 + t0 + c];
  __syncthreads();

  const float* ar[4];
#pragma unroll
  for (int i = 0; i < 4; i++) ar[i] = xs + (size_t)(r * 4 + i) * NP;

  float accv[4] = {0.f, 0.f, 0.f, 0.f};
  float accj[4] = {0.f, 0.f, 0.f, 0.f};
  float4 ac[4], an[4];
#pragma unroll
  for (int i = 0; i < 4; i++) ac[i] = *(const float4*)(ar[i]);

  for (int k = 0;; k += 4) {
    const bool more = (k + 4 < NP);
    if (more) {
#pragma unroll
      for (int i = 0; i < 4; i++) an[i] = *(const float4*)(ar[i] + k + 4);
    }
    const float4 b01 = *(const float4*)(&Bs[c][k]);      // (v_k, j_k, v_k1, j_k1)
    const float4 b23 = *(const float4*)(&Bs[c][k + 2]);
#pragma unroll
    for (int i = 0; i < 4; i++) {
      accv[i] = fmaf(ac[i].x, b01.x, accv[i]); accj[i] = fmaf(ac[i].x, b01.y, accj[i]);
      accv[i] = fmaf(ac[i].y, b01.z, accv[i]); accj[i] = fmaf(ac[i].y, b01.w, accj[i]);
      accv[i] = fmaf(ac[i].z, b23.x, accv[i]); accj[i] = fmaf(ac[i].z, b23.y, accj[i]);
      accv[i] = fmaf(ac[i].w, b23.z, accv[i]); accj[i] = fmaf(ac[i].w, b23.w, accj[i]);
    }
    if (!more) break;
#pragma unroll
    for (int i = 0; i < 4; i++) ac[i] = an[i];
  }

  // fused elementwise epilogue
  float es_p[4], sw_p[4];
#pragma unroll
  for (int i = 0; i < 4; i++) {
    const float g1v = accv[i], g2v = accj[i];
    float d2 = fmaxf(f4c(uu4, i) - 2.f * g1v + vvt, 0.f);
    float xd = QC * sqrtf(d2);
    float dv = QC * (g2v - c1t);
    float ex = EXPC * __expf(-xd);
    float e1v = ex * (1.f + xd);
    float w_ = ex * dv;
    ws[OFF_W + (size_t)(r * 4 + i) * NT + t0 + c] = w_;
    ws[OFF_E1 + (size_t)(r * 4 + i) * NT + t0 + c] = e1v;
    es_p[i] = e1v * dv;
    sw_p[i] = w_;
  }
#pragma unroll
  for (int off = 8; off; off >>= 1) {
#pragma unroll
    for (int i = 0; i < 4; i++) {
      es_p[i] += __shfl_down(es_p[i], off, 16);
      sw_p[i] += __shfl_down(sw_p[i], off, 16);
    }
  }
  if (c == 0) {
#pragma unroll
    for (int i = 0; i < 4; i++) {
      atomicAdd(ws + OFF_ES + r * 4 + i, es_p[i]);
      atomicAdd(ws + OFF_SW + r * 4 + i, sw_p[i]);
    }
  }
}

// ---------- kernel 3: GEMM2 F1p = w @ xt, F2 = e1 @ Ja ----------
// out tile 64m x 32p; K-chunk 120 fully staged in LDS once; A (w,e1) streamed
// with register double-buffer; NO barriers in K-loop; atomic K-reduction.
#define G2_KC 120
#define G2_STR 34   // float2 per k-row (32 + 2 pad); 68 floats, 68%32=4
__global__ __launch_bounds__(256) void k_g2(const float* __restrict__ xt,
                                            const float* __restrict__ Ja,
                                            float* __restrict__ ws) {
  __shared__ __align__(16) float2 Bs[G2_KC][G2_STR];
  const int tid = threadIdx.x;
  const int p0 = blockIdx.x * 32;
  const int k0 = blockIdx.y * G2_KC;
  const int c = tid & 15;   // p-pair: p = p0 + 2c + {0,1}
  const int r = tid >> 4;   // m-group: m = 4r..4r+3

  // stage B chunk
  {
    const int kr = tid >> 4;
    const int kg = tid & 15;
    const int p = p0 + kg * 2;
#pragma unroll
    for (int pass = 0; pass < 8; pass++) {
      const int krow = kr + pass * 16;
      if (krow < G2_KC) {
        float4 val = make_float4(0.f, 0.f, 0.f, 0.f);
        if (p + 1 < NP) {
          const float2 v = *(const float2*)(xt + (size_t)(k0 + krow) * NP + p);
          const float2 j = *(const float2*)(Ja + (size_t)(k0 + krow) * NP + p);
          val = make_float4(v.x, j.x, v.y, j.y);
        }
        *(float4*)(&Bs[krow][kg * 2]) = val;
      }
    }
  }
  __syncthreads();

  const float* wr[4];
  const float* er[4];
#pragma unroll
  for (int i = 0; i < 4; i++) {
    wr[i] = ws + OFF_W  + (size_t)(r * 4 + i) * NT + k0;
    er[i] = ws + OFF_E1 + (size_t)(r * 4 + i) * NT + k0;
  }
  float acc1[2][4] = {{0.f,0.f,0.f,0.f},{0.f,0.f,0.f,0.f}};
  float acc2[2][4] = {{0.f,0.f,0.f,0.f},{0.f,0.f,0.f,0.f}};
  float4 wc[4], ec[4], wn[4], en[4];
#pragma unroll
  for (int i = 0; i < 4; i++) {
    wc[i] = *(const float4*)(wr[i]);
    ec[i] = *(const float4*)(er[i]);
  }

  for (int k = 0;; k += 4) {
    const bool more = (k + 4 < G2_KC);
    if (more) {
#pragma unroll
      for (int i = 0; i < 4; i++) {
        wn[i] = *(const float4*)(wr[i] + k + 4);
        en[i] = *(const float4*)(er[i] + k + 4);
      }
    }
#pragma unroll
    for (int kk = 0; kk < 4; kk++) {
      const float4 b = *(const float4*)(&Bs[k + kk][c * 2]);  // (v0,j0,v1,j1)
#pragma unroll
      for (int i = 0; i < 4; i++) {
        const float aw = f4c(wc[i], kk);
        const float ae = f4c(ec[i], kk);
        acc1[0][i] = fmaf(aw, b.x, acc1[0][i]);
        acc2[0][i] = fmaf(ae, b.y, acc2[0][i]);
        acc1[1][i] = fmaf(aw, b.z, acc1[1][i]);
        acc2[1][i] = fmaf(ae, b.w, acc2[1][i]);
      }
    }
    if (!more) break;
#pragma unroll
    for (int i = 0; i < 4; i++) { wc[i] = wn[i]; ec[i] = en[i]; }
  }

  float* F1p = ws + OFF_F1P;
  float* F2  = ws + OFF_F2;
#pragma unroll
  for (int pp = 0; pp < 2; pp++) {
    const int p = p0 + c * 2 + pp;
    if (p < NP) {
#pragma unroll
      for (int i = 0; i < 4; i++) {
        atomicAdd(&F1p[(r * 4 + i) * NP + p], acc1[pp][i]);
        atomicAdd(&F2[(r * 4 + i) * NP + p],  acc2[pp][i]);
      }
    }
  }
}

// ---------- kernel 4: finalize ----------
__global__ __launch_bounds__(320) void k_final(const float* __restrict__ Rs,
                                               const float* __restrict__ ws,
                                               float* __restrict__ out) {
  const int m = blockIdx.x;
  const int tid = threadIdx.x;
  __shared__ float fx[NP];
  __shared__ float sR[NA * 3];
  if (tid < NA * 3) sR[tid] = Rs[m * NA * 3 + tid];
  const float sw = ws[OFF_SW + m];
  for (int p = tid; p < NP; p += 320) {
    float u = ws[OFF_XS + m * NP + p];
    float F1 = QC * (u * sw - ws[OFF_F1P + m * NP + p]);
    fx[p] = (F1 - ws[OFF_F2 + m * NP + p]) * u * u * u;
  }
  __syncthreads();
  if (tid == 0) out[m] = ws[OFF_ES + m] / QC;  // *STD + C, STD=1, C=0
  if (tid < NA * 3) {
    const int a = tid / 3, cc = tid % 3;
    const float ra = sR[a * 3 + cc];
    float acc = 0.f;
    for (int b = 0; b < NA; b++) {
      if (b == a) continue;
      const int i = a > b ? a : b, j = a > b ? b : a;
      const int p = i * (i - 1) / 2 + j;
      acc += (sR[b * 3 + cc] - ra) * fx[p];
    }
    out[MM + m * NA * 3 + tid] = acc;
  }
}

extern "C" void kernel_launch(void* const* d_in, const int* in_sizes, int n_in,
                              void* d_out, int out_size, void* d_ws, size_t ws_size,
                              hipStream_t stream) {
  const float* Rs = (const float*)d_in[0];
  const float* xt = (const float*)d_in[1];
  const float* Ja = (const float*)d_in[2];
  float* out = (float*)d_out;
  float* ws = (float*)d_ws;

  k_pre<<<MM + NT / 4, 256, 0, stream>>>(Rs, xt, Ja, ws);
  k_g1<<<NT / G1_TD, 256, 0, stream>>>(xt, Ja, ws);
  k_g2<<<dim3(9, NT / G2_KC), 256, 0, stream>>>(xt, Ja, ws);
  k_final<<<MM, 320, 0, stream>>>(Rs, ws, out);
}